// Round 1
// baseline (402.468 us; speedup 1.0000x reference)
//
#include <hip/hip_runtime.h>

// LGAE fused pipeline:
//   1. xw_kernel:   XW = X @ W (fp32), epilogue splits each fp32 into bf16 hi/lo
//                   and stores in zgemm B-fragment order (chunked, slot-swizzled).
//   2. w23_kernel:  w23 = weight_two @ weight_three  (256 floats)
//   3. zgemm_kernel: Z = adj @ XW via 3-term bf16 MFMA split (hi*hi + hi*lo + lo*hi),
//                   K-split across blocks into fp32 partial buffers.
//   4. nodered_kernel: a[n] = relu(Z[n,:]).w23[:128], b[n] = relu(Z[n,:]).w23[128:]
//   5. edge_kernel: out[e] = sigmoid(a[i]+b[j])
//
// Algebraic collapse: relu(zpair) @ W2 @ W3 == relu(zpair) @ (W2 @ W3), and
// zpair = [Z[i], Z[j]] so h[e] = a[i] + b[j].

#define N_NODES 16384
#define IN_DIM  512
#define HID     128
#define E_POS_N 524288
#define E_TOT   1048576

typedef __bf16 bf16x8 __attribute__((ext_vector_type(8)));
typedef float  f32x4  __attribute__((ext_vector_type(4)));
typedef unsigned short us8 __attribute__((ext_vector_type(8)));

__device__ __forceinline__ bf16x8 ldsb(const unsigned short* p){
  return __builtin_bit_cast(bf16x8, *reinterpret_cast<const us8*>(p));
}

__device__ __forceinline__ void gload16(const void* g, void* l){
  __builtin_amdgcn_global_load_lds(
      (const __attribute__((address_space(1))) unsigned int*)g,
      (__attribute__((address_space(3))) unsigned int*)l,
      16, 0, 0);
}

// split fp32 -> (hi = truncate-to-bf16, lo = RN(a - hi)); lo is exact residual,
// dropped lo*lo term is ~2^-16 relative -> Z err std ~1e-3, h err ~6e-4.
__device__ __forceinline__ void split8(const float* f, uint4& hi, uint4& lo){
  unsigned hu[8], lu[8];
#pragma unroll
  for (int i = 0; i < 8; ++i){
    unsigned b  = __float_as_uint(f[i]);
    unsigned hb = b & 0xFFFF0000u;
    hu[i] = hb >> 16;
    float lf = f[i] - __uint_as_float(hb);
    __bf16 lb = (__bf16)lf;
    lu[i] = (unsigned)__builtin_bit_cast(unsigned short, lb);
  }
  hi = make_uint4(hu[0]|(hu[1]<<16), hu[2]|(hu[3]<<16), hu[4]|(hu[5]<<16), hu[6]|(hu[7]<<16));
  lo = make_uint4(lu[0]|(lu[1]<<16), lu[2]|(lu[3]<<16), lu[4]|(lu[5]<<16), lu[6]|(lu[7]<<16));
}

// ---------------- kernel 1: XW = X @ W, fp32, split+transposed epilogue -------
// BM=64 rows/block, all 128 cols, BK=32; 256 threads, thread tile 8x4.
__global__ __launch_bounds__(256) void xw_kernel(const float* __restrict__ X,
                                                 const float* __restrict__ W,
                                                 unsigned short* __restrict__ bfH,
                                                 unsigned short* __restrict__ bfL){
  __shared__ float Xt[32][64];    // transposed X tile [k][row]
  __shared__ float Ws[32][128];   // W tile [k][col]
  const int tid = threadIdx.x;
  const int m0  = blockIdx.x * 64;
  const int ty  = tid >> 5;       // 0..7  -> rows ty*8..+7
  const int tx  = tid & 31;       // cols tx*4..+3
  const int sr  = tid >> 2;       // stage: row 0..63
  const int sq  = tid & 3;        // stage: k octet
  const int wk  = tid >> 3;       // W stage row 0..31
  const int wc  = (tid & 7) * 16; // W stage col
  float acc[8][4] = {};
  for (int kt = 0; kt < 16; ++kt){
    const int k0 = kt * 32;
    __syncthreads();
    {
      const float* xp = X + (size_t)(m0 + sr) * IN_DIM + k0 + sq * 8;
      float4 x0 = *(const float4*)xp;
      float4 x1 = *(const float4*)(xp + 4);
      Xt[sq*8+0][sr] = x0.x; Xt[sq*8+1][sr] = x0.y; Xt[sq*8+2][sr] = x0.z; Xt[sq*8+3][sr] = x0.w;
      Xt[sq*8+4][sr] = x1.x; Xt[sq*8+5][sr] = x1.y; Xt[sq*8+6][sr] = x1.z; Xt[sq*8+7][sr] = x1.w;
      const float* wp = W + (size_t)(k0 + wk) * HID + wc;
      *(float4*)&Ws[wk][wc+0]  = *(const float4*)(wp + 0);
      *(float4*)&Ws[wk][wc+4]  = *(const float4*)(wp + 4);
      *(float4*)&Ws[wk][wc+8]  = *(const float4*)(wp + 8);
      *(float4*)&Ws[wk][wc+12] = *(const float4*)(wp + 12);
    }
    __syncthreads();
#pragma unroll 8
    for (int kk = 0; kk < 32; ++kk){
      float4 a0 = *(const float4*)&Xt[kk][ty*8];
      float4 a1 = *(const float4*)&Xt[kk][ty*8+4];
      float4 b  = *(const float4*)&Ws[kk][tx*4];
      float av[8] = {a0.x,a0.y,a0.z,a0.w,a1.x,a1.y,a1.z,a1.w};
      float bv[4] = {b.x,b.y,b.z,b.w};
#pragma unroll
      for (int i = 0; i < 8; ++i)
#pragma unroll
        for (int c = 0; c < 4; ++c)
          acc[i][c] = fmaf(av[i], bv[c], acc[i][c]);
    }
  }
  // epilogue: thread holds 8 consecutive rows (k-dim of zgemm B) x 4 cols.
  // Bfrag layout: chunk t (32 k) = [col c][slot][8 k] with slot = g ^ ((c>>1)&3).
  const int row0 = m0 + ty * 8;
  const size_t tI = (size_t)(row0 >> 5);
  const int gI = (row0 >> 3) & 3;
#pragma unroll
  for (int cc = 0; cc < 4; ++cc){
    const int c = tx * 4 + cc;
    const int slot = gI ^ ((c >> 1) & 3);
    float f[8];
#pragma unroll
    for (int i = 0; i < 8; ++i) f[i] = acc[i][cc];
    uint4 hi, lo; split8(f, hi, lo);
    const size_t off = tI * 4096 + (size_t)c * 32 + slot * 8;
    *(uint4*)(bfH + off) = hi;
    *(uint4*)(bfL + off) = lo;
  }
}

// ---------------- kernel 2: w23 = W2 @ W3 (256 x 1) ---------------------------
__global__ void w23_kernel(const float* __restrict__ w2, const float* __restrict__ w3,
                           float* __restrict__ w23){
  const int t = threadIdx.x; // 256 threads
  float acc = 0.f;
#pragma unroll 4
  for (int k = 0; k < HID; ++k) acc = fmaf(w2[t * HID + k], w3[k], acc);
  w23[t] = acc;
}

// ---------------- kernel 3: Z = adj @ XW, bf16x3 MFMA, K-split ----------------
// BM=128, BN=128, BK=32; 512 threads = 8 waves (2M x 4N), 4x2 16x16 frags/wave.
// adj staged via regs (fp32 -> hi/lo bf16) with XOR slot swizzle; XW tiles via
// global_load_lds from the pre-split, pre-swizzled Bfrag arrays.
__global__ __launch_bounds__(512, 4) void zgemm_kernel(const float* __restrict__ adj,
                                                       const unsigned short* __restrict__ bfH,
                                                       const unsigned short* __restrict__ bfL,
                                                       float* __restrict__ part,
                                                       int ksplit){
  __shared__ alignas(16) unsigned short sA[2][2][128 * 32]; // [buf][hi/lo]
  __shared__ alignas(16) unsigned short sB[2][2][128 * 32];
  const int tid  = threadIdx.x;
  const int lane = tid & 63;
  const int w    = tid >> 6;     // 0..7
  const int wr   = w >> 2;       // 0..1 -> 64-row half
  const int wcn  = w & 3;        // 0..3 -> 32-col quarter
  const int mt   = blockIdx.x & 127;
  const int s    = blockIdx.x >> 7;
  const int klen = N_NODES / ksplit;
  const int k0   = s * klen;
  const int nt   = klen / 32;

  const int ar   = tid >> 2;     // staged adj row 0..127
  const int ak8  = tid & 3;      // k octet
  const int aoff = ar * 32 + (ak8 ^ ((ar >> 1) & 3)) * 8;
  const float* adjp = adj + (size_t)(mt * 128 + ar) * N_NODES + k0 + ak8 * 8;
  const int w512 = w * 512;

  const int g = lane >> 4;
  int a_off[4], b_off[2];
#pragma unroll
  for (int m = 0; m < 4; ++m){
    int rA = wr * 64 + m * 16 + (lane & 15);
    a_off[m] = rA * 32 + ((g ^ ((rA >> 1) & 3)) << 3);
  }
#pragma unroll
  for (int n = 0; n < 2; ++n){
    int cB = wcn * 32 + n * 16 + (lane & 15);
    b_off[n] = cB * 32 + ((g ^ ((cB >> 1) & 3)) << 3);
  }

  f32x4 acc[4][2] = {};

  { // prologue: stage t=0 into buf 0
    const size_t chunk = (size_t)(k0 >> 5) * 4096;
    gload16(bfH + chunk + (size_t)tid * 8, &sB[0][0][w512]);
    gload16(bfL + chunk + (size_t)tid * 8, &sB[0][1][w512]);
    float4 f0 = *(const float4*)adjp;
    float4 f1 = *(const float4*)(adjp + 4);
    float f[8] = {f0.x,f0.y,f0.z,f0.w,f1.x,f1.y,f1.z,f1.w};
    uint4 hi, lo; split8(f, hi, lo);
    *(uint4*)&sA[0][0][aoff] = hi;
    *(uint4*)&sA[0][1][aoff] = lo;
  }
  __syncthreads();

  for (int t = 0; t < nt; ++t){
    const int cur = t & 1;
    const int nxt = cur ^ 1;
    const bool pf = (t + 1 < nt);
    float4 f0, f1;
    if (pf){ // issue next-tile loads early; convert+write after compute (latency hides)
      const size_t chunk = (size_t)((k0 >> 5) + t + 1) * 4096;
      gload16(bfH + chunk + (size_t)tid * 8, &sB[nxt][0][w512]);
      gload16(bfL + chunk + (size_t)tid * 8, &sB[nxt][1][w512]);
      const float* ap = adjp + (size_t)(t + 1) * 32;
      f0 = *(const float4*)ap;
      f1 = *(const float4*)(ap + 4);
    }
    { // compute on cur
      bf16x8 aH[4], aL[4], bH[2], bL[2];
#pragma unroll
      for (int m = 0; m < 4; ++m){
        aH[m] = ldsb(&sA[cur][0][a_off[m]]);
        aL[m] = ldsb(&sA[cur][1][a_off[m]]);
      }
#pragma unroll
      for (int n = 0; n < 2; ++n){
        bH[n] = ldsb(&sB[cur][0][b_off[n]]);
        bL[n] = ldsb(&sB[cur][1][b_off[n]]);
      }
#pragma unroll
      for (int m = 0; m < 4; ++m){
#pragma unroll
        for (int n = 0; n < 2; ++n){
          acc[m][n] = __builtin_amdgcn_mfma_f32_16x16x32_bf16(aH[m], bH[n], acc[m][n], 0, 0, 0);
          acc[m][n] = __builtin_amdgcn_mfma_f32_16x16x32_bf16(aH[m], bL[n], acc[m][n], 0, 0, 0);
          acc[m][n] = __builtin_amdgcn_mfma_f32_16x16x32_bf16(aL[m], bH[n], acc[m][n], 0, 0, 0);
        }
      }
    }
    if (pf){
      float f[8] = {f0.x,f0.y,f0.z,f0.w,f1.x,f1.y,f1.z,f1.w};
      uint4 hi, lo; split8(f, hi, lo);
      *(uint4*)&sA[nxt][0][aoff] = hi;
      *(uint4*)&sA[nxt][1][aoff] = lo;
    }
    __syncthreads();
  }

  // epilogue: C/D layout col = lane&15, row = (lane>>4)*4 + j   [guide m89]
  float* pbase = part + (size_t)s * ((size_t)N_NODES * HID);
  const int row0 = mt * 128 + wr * 64;
  const int colw = wcn * 32;
#pragma unroll
  for (int m = 0; m < 4; ++m){
#pragma unroll
    for (int n = 0; n < 2; ++n){
#pragma unroll
      for (int j = 0; j < 4; ++j){
        const int row = row0 + m * 16 + (lane >> 4) * 4 + j;
        const int col = colw + n * 16 + (lane & 15);
        pbase[(size_t)row * HID + col] = acc[m][n][j];
      }
    }
  }
}

// ---------------- kernel 4: a[n], b[n] = relu(Z[n,:]) . w23 halves ------------
__global__ __launch_bounds__(256) void nodered_kernel(const float* __restrict__ part,
                                                      const float* __restrict__ w23,
                                                      float* __restrict__ aarr,
                                                      float* __restrict__ barr,
                                                      int ksplit){
  const int lane = threadIdx.x & 63;
  const int wv   = threadIdx.x >> 6;
  const int n    = blockIdx.x * 4 + wv;
  const float* p = part + (size_t)n * HID;
  float z1 = 0.f, z2 = 0.f;
  for (int s = 0; s < ksplit; ++s){
    const size_t o = (size_t)s * N_NODES * HID;
    z1 += p[o + lane];
    z2 += p[o + lane + 64];
  }
  z1 = fmaxf(z1, 0.f); z2 = fmaxf(z2, 0.f);
  float av = z1 * w23[lane]       + z2 * w23[lane + 64];
  float bv = z1 * w23[128 + lane] + z2 * w23[192 + lane];
#pragma unroll
  for (int o = 32; o > 0; o >>= 1){
    av += __shfl_down(av, o);
    bv += __shfl_down(bv, o);
  }
  if (lane == 0){ aarr[n] = av; barr[n] = bv; }
}

// ---------------- kernel 5: out[e] = sigmoid(a[i] + b[j]) ---------------------
__global__ __launch_bounds__(256) void edge_kernel(const int* __restrict__ e0,
                                                   const int* __restrict__ e1,
                                                   const float* __restrict__ aarr,
                                                   const float* __restrict__ barr,
                                                   float* __restrict__ out){
  const int e = blockIdx.x * 256 + threadIdx.x;
  int i, j;
  if (e < E_POS_N){ i = e0[2 * e];  j = e0[2 * e + 1]; }
  else { const int ee = e - E_POS_N; i = e1[2 * ee]; j = e1[2 * ee + 1]; }
  const float h = aarr[i] + barr[j];
  out[e] = 1.0f / (1.0f + __expf(-h));
}

extern "C" void kernel_launch(void* const* d_in, const int* in_sizes, int n_in,
                              void* d_out, int out_size, void* d_ws, size_t ws_size,
                              hipStream_t stream){
  const float* X   = (const float*)d_in[0];
  const float* adj = (const float*)d_in[1];
  const float* W   = (const float*)d_in[2];
  const float* W2  = (const float*)d_in[3];
  const float* W3  = (const float*)d_in[4];
  const int*   e0  = (const int*)d_in[5];
  const int*   e1  = (const int*)d_in[6];
  float* out = (float*)d_out;

  char* wsb = (char*)d_ws;
  unsigned short* bfH = (unsigned short*)(wsb);                              // 4 MB
  unsigned short* bfL = (unsigned short*)(wsb + (size_t)4 * 1024 * 1024);    // 4 MB
  float* w23  = (float*)(wsb + (size_t)8 * 1024 * 1024);                     // 1 KB
  float* aarr = (float*)(wsb + (size_t)8 * 1024 * 1024 + 65536);             // 64 KB
  float* barr = (float*)(wsb + (size_t)8 * 1024 * 1024 + 2 * 65536);         // 64 KB
  float* part = (float*)(wsb + (size_t)16 * 1024 * 1024);                    // ksplit * 8 MB

  const size_t PART = (size_t)N_NODES * HID * 4;
  const size_t base = (size_t)16 * 1024 * 1024;
  int ksplit = 1;
  if (ws_size >= base + 4 * PART) ksplit = 4;
  else if (ws_size >= base + 2 * PART) ksplit = 2;

  hipLaunchKernelGGL(xw_kernel, dim3(N_NODES / 64), dim3(256), 0, stream, X, W, bfH, bfL);
  hipLaunchKernelGGL(w23_kernel, dim3(1), dim3(256), 0, stream, W2, W3, w23);
  hipLaunchKernelGGL(zgemm_kernel, dim3(128 * ksplit), dim3(512), 0, stream,
                     adj, bfH, bfL, part, ksplit);
  hipLaunchKernelGGL(nodered_kernel, dim3(N_NODES / 4), dim3(256), 0, stream,
                     part, w23, aarr, barr, ksplit);
  hipLaunchKernelGGL(edge_kernel, dim3(E_TOT / 256), dim3(256), 0, stream,
                     e0, e1, aarr, barr, out);
}

// Round 2
// 312.433 us; speedup vs baseline: 1.2882x; 1.2882x over previous
//
#include <hip/hip_runtime.h>

// LGAE fused pipeline (R1: counted-vmcnt triple-buffered zgemm):
//   1. xw_kernel:  XW = X @ W (fp32); epilogue splits fp32 -> bf16 hi/lo and
//      stores a pre-swizzled LDS image (16KB per k-tile of 32) so zgemm can
//      global_load_lds it linearly.
//   2. w23_kernel: w23 = W2 @ W3 (256 floats)
//   3. zgemm_kernel: Z = adj @ XW, 3-term bf16 split (hi*hi + hi*lo + lo*hi).
//      adj staged as RAW FP32 via global_load_lds (same LDS bytes as hi+lo bf16),
//      split at fragment-read time. 3 LDS buffers, prefetch depth 2,
//      s_waitcnt vmcnt(6) (T4 counted), raw s_barrier, setprio (T5).
//   4. nodered_kernel: a[n]=relu(Z[n]).w23[:128], b[n]=relu(Z[n]).w23[128:]
//   5. edge_kernel: out[e] = sigmoid(a[i]+b[j])

#define N_NODES 16384
#define IN_DIM  512
#define HID     128
#define E_POS_N 524288
#define E_TOT   1048576

typedef __bf16 bf16x8 __attribute__((ext_vector_type(8)));
typedef float  f32x4  __attribute__((ext_vector_type(4)));
typedef unsigned short us8 __attribute__((ext_vector_type(8)));

__device__ __forceinline__ bf16x8 ldsb(const void* p){
  return __builtin_bit_cast(bf16x8, *reinterpret_cast<const us8*>(p));
}
__device__ __forceinline__ void gload16(const void* g, void* l){
  __builtin_amdgcn_global_load_lds(
      (const __attribute__((address_space(1))) unsigned int*)g,
      (__attribute__((address_space(3))) unsigned int*)l, 16, 0, 0);
}

// fp32 -> (hi = truncate-to-bf16, lo = RN(f - hi)). Dropped lo*lo is ~2^-16 rel.
__device__ __forceinline__ void split8(const float* f, bf16x8& hi, bf16x8& lo){
  unsigned short h[8];
  __bf16 l[8];
#pragma unroll
  for (int i = 0; i < 8; ++i){
    unsigned u  = __float_as_uint(f[i]);
    unsigned hb = u & 0xFFFF0000u;
    h[i] = (unsigned short)(hb >> 16);
    l[i] = (__bf16)(f[i] - __uint_as_float(hb));
  }
  us8 hv = {h[0], h[1], h[2], h[3], h[4], h[5], h[6], h[7]};
  hi = __builtin_bit_cast(bf16x8, hv);
  bf16x8 lv = {l[0], l[1], l[2], l[3], l[4], l[5], l[6], l[7]};
  lo = lv;
}

// ---------------- kernel 1: XW = X @ W, fp32, split + pre-swizzled epilogue ---
// Global bfB layout: per k-tile t (32 k): 16KB block = [col c][128B] where the
// 128B row holds 8 16B slots: slot for (hl,g) at offset ((hl*64 + g*16) ^ ((c&7)<<4)).
__global__ __launch_bounds__(256) void xw_kernel(const float* __restrict__ X,
                                                 const float* __restrict__ W,
                                                 unsigned short* __restrict__ bfB){
  __shared__ float Xt[32][64];
  __shared__ float Ws[32][128];
  const int tid = threadIdx.x;
  const int m0  = blockIdx.x * 64;
  const int ty  = tid >> 5;
  const int tx  = tid & 31;
  const int sr  = tid >> 2;
  const int sq  = tid & 3;
  const int wk  = tid >> 3;
  const int wc  = (tid & 7) * 16;
  float acc[8][4] = {};
  for (int kt = 0; kt < 16; ++kt){
    const int k0 = kt * 32;
    __syncthreads();
    {
      const float* xp = X + (size_t)(m0 + sr) * IN_DIM + k0 + sq * 8;
      float4 x0 = *(const float4*)xp;
      float4 x1 = *(const float4*)(xp + 4);
      Xt[sq*8+0][sr] = x0.x; Xt[sq*8+1][sr] = x0.y; Xt[sq*8+2][sr] = x0.z; Xt[sq*8+3][sr] = x0.w;
      Xt[sq*8+4][sr] = x1.x; Xt[sq*8+5][sr] = x1.y; Xt[sq*8+6][sr] = x1.z; Xt[sq*8+7][sr] = x1.w;
      const float* wp = W + (size_t)(k0 + wk) * HID + wc;
      *(float4*)&Ws[wk][wc+0]  = *(const float4*)(wp + 0);
      *(float4*)&Ws[wk][wc+4]  = *(const float4*)(wp + 4);
      *(float4*)&Ws[wk][wc+8]  = *(const float4*)(wp + 8);
      *(float4*)&Ws[wk][wc+12] = *(const float4*)(wp + 12);
    }
    __syncthreads();
#pragma unroll 8
    for (int kk = 0; kk < 32; ++kk){
      float4 a0 = *(const float4*)&Xt[kk][ty*8];
      float4 a1 = *(const float4*)&Xt[kk][ty*8+4];
      float4 b  = *(const float4*)&Ws[kk][tx*4];
      float av[8] = {a0.x,a0.y,a0.z,a0.w,a1.x,a1.y,a1.z,a1.w};
      float bv[4] = {b.x,b.y,b.z,b.w};
#pragma unroll
      for (int i = 0; i < 8; ++i)
#pragma unroll
        for (int c = 0; c < 4; ++c)
          acc[i][c] = fmaf(av[i], bv[c], acc[i][c]);
    }
  }
  const int row0 = m0 + ty * 8;           // k index, multiple of 8
  const int tile = row0 >> 5;
  const int g    = (row0 >> 3) & 3;
#pragma unroll
  for (int cc = 0; cc < 4; ++cc){
    const int c  = tx * 4 + cc;
    const int sw = (c & 7) << 4;
    float f[8];
#pragma unroll
    for (int i = 0; i < 8; ++i) f[i] = acc[i][cc];
    bf16x8 hi, lo; split8(f, hi, lo);
    char* tb = (char*)bfB + (size_t)tile * 16384 + (size_t)c * 128;
    *(us8*)(tb + ((g * 16) ^ sw))      = __builtin_bit_cast(us8, hi);
    *(us8*)(tb + ((64 + g * 16) ^ sw)) = __builtin_bit_cast(us8, lo);
  }
}

// ---------------- kernel 2: w23 = W2 @ W3 (256 x 1) ---------------------------
__global__ void w23_kernel(const float* __restrict__ w2, const float* __restrict__ w3,
                           float* __restrict__ w23){
  const int t = threadIdx.x;
  float acc = 0.f;
#pragma unroll 4
  for (int k = 0; k < HID; ++k) acc = fmaf(w2[t * HID + k], w3[k], acc);
  w23[t] = acc;
}

// ---------------- kernel 3: Z = adj @ XW -------------------------------------
// BM=256, BN=128, BK=32; 512 threads = 8 waves (4M x 2N), wave tile 64x64,
// acc[4][4] 16x16 frags. LDS per buf: A fp32 256x32 = 32KB (rows 128B,
// source pre-XOR-swizzled), B bf16 hi/lo 16KB (pre-swizzled global image). x3 bufs.
__global__ __launch_bounds__(512, 2) void zgemm_kernel(const float* __restrict__ adj,
                                                       const unsigned short* __restrict__ bfB,
                                                       float* __restrict__ part,
                                                       int ksplit){
  __shared__ alignas(16) char lds[3][49152];
  const int tid  = threadIdx.x;
  const int lane = tid & 63;
  const int w    = tid >> 6;
  const int wm   = w >> 1;       // 0..3 -> 64-row group
  const int wn   = w & 1;        // 0..1 -> 64-col group
  int mt, s;
  if (ksplit == 4){ // 2 XCDs per k-slice: slice's 2MB B image stays L2-resident
    const int xcd = blockIdx.x & 7, idx = blockIdx.x >> 3;
    s = xcd & 3; mt = ((xcd >> 2) << 5) + idx;
  } else { mt = blockIdx.x & 63; s = blockIdx.x >> 6; }
  const int klen = N_NODES / ksplit;
  const int k0   = s * klen;
  const int nt   = klen >> 5;

  const int g = lane >> 4, l15 = lane & 15;
  int aoff[4][2], boffH[4], boffL[4];
#pragma unroll
  for (int m = 0; m < 4; ++m){
    const int r = wm * 64 + m * 16 + l15;
    const int sw = (r & 7) << 4;
    aoff[m][0] = r * 128 + ((g * 32) ^ sw);
    aoff[m][1] = r * 128 + ((g * 32 + 16) ^ sw);
  }
#pragma unroll
  for (int n = 0; n < 4; ++n){
    const int c = wn * 64 + n * 16 + l15;
    const int sw = (c & 7) << 4;
    boffH[n] = 32768 + c * 128 + ((g * 16) ^ sw);
    boffL[n] = 32768 + c * 128 + ((64 + g * 16) ^ sw);
  }

  // stage sources: A per-lane global addr carries the inverse swizzle (rule 21)
  const char* asrc[4]; int aldo[4];
#pragma unroll
  for (int c4 = 0; c4 < 4; ++c4){
    const int r = c4 * 64 + (tid >> 3);
    asrc[c4] = (const char*)adj + ((size_t)(mt * 256 + r) * N_NODES + k0) * 4
               + (((tid & 7) * 16) ^ ((r & 7) << 4));
    aldo[c4] = c4 * 8192 + tid * 16;
  }
  const char* bsrc = (const char*)bfB + (size_t)(k0 >> 5) * 16384 + tid * 16;

#define STAGE(buf, tt) do { \
    _Pragma("unroll") \
    for (int c4 = 0; c4 < 4; ++c4) \
      gload16(asrc[c4] + (size_t)(tt) * 128, (buf) + aldo[c4]); \
    gload16(bsrc + (size_t)(tt) * 16384,        (buf) + 32768 + tid * 16); \
    gload16(bsrc + (size_t)(tt) * 16384 + 8192, (buf) + 40960 + tid * 16); \
  } while (0)

  f32x4 acc[4][4] = {};

  auto compute = [&](const char* bp){
    bf16x8 bHv[4], bLv[4];
#pragma unroll
    for (int n = 0; n < 4; ++n){
      bHv[n] = ldsb(bp + boffH[n]);
      bLv[n] = ldsb(bp + boffL[n]);
    }
#pragma unroll
    for (int m = 0; m < 4; ++m){
      f32x4 v0 = *(const f32x4*)(bp + aoff[m][0]);
      f32x4 v1 = *(const f32x4*)(bp + aoff[m][1]);
      float f[8] = {v0[0], v0[1], v0[2], v0[3], v1[0], v1[1], v1[2], v1[3]};
      bf16x8 aH, aL; split8(f, aH, aL);
      __builtin_amdgcn_s_setprio(1);
#pragma unroll
      for (int n = 0; n < 4; ++n)
        acc[m][n] = __builtin_amdgcn_mfma_f32_16x16x32_bf16(aH, bHv[n], acc[m][n], 0, 0, 0);
#pragma unroll
      for (int n = 0; n < 4; ++n)
        acc[m][n] = __builtin_amdgcn_mfma_f32_16x16x32_bf16(aH, bLv[n], acc[m][n], 0, 0, 0);
#pragma unroll
      for (int n = 0; n < 4; ++n)
        acc[m][n] = __builtin_amdgcn_mfma_f32_16x16x32_bf16(aL, bHv[n], acc[m][n], 0, 0, 0);
      __builtin_amdgcn_s_setprio(0);
    }
  };

  char* pc = lds[0]; char* pn = lds[1]; char* pf = lds[2];
  STAGE(pc, 0);
  STAGE(pn, 1);
  asm volatile("s_waitcnt vmcnt(6)" ::: "memory");   // tile 0 landed
  __builtin_amdgcn_s_barrier();
  asm volatile("" ::: "memory");

  for (int t = 0; t < nt; ++t){
    if (t + 2 < nt) STAGE(pf, t + 2);
    compute(pc);
    if (t + 2 < nt)      asm volatile("s_waitcnt vmcnt(6)" ::: "memory"); // t+1 landed, t+2 in flight
    else if (t + 1 < nt) asm volatile("s_waitcnt vmcnt(0)" ::: "memory"); // drain last prefetch
    if (t + 1 < nt){
      __builtin_amdgcn_s_barrier();
      asm volatile("" ::: "memory");
    }
    char* tmp = pc; pc = pn; pn = pf; pf = tmp;
  }
#undef STAGE

  // C/D layout: col = lane&15, row = (lane>>4)*4 + j   [guide m89]
  float* pb = part + (size_t)s * ((size_t)N_NODES * HID);
  const int row0 = mt * 256 + wm * 64;
  const int col0 = wn * 64;
#pragma unroll
  for (int m = 0; m < 4; ++m){
#pragma unroll
    for (int n = 0; n < 4; ++n){
#pragma unroll
      for (int j = 0; j < 4; ++j){
        const int row = row0 + m * 16 + (lane >> 4) * 4 + j;
        const int col = col0 + n * 16 + l15;
        pb[(size_t)row * HID + col] = acc[m][n][j];
      }
    }
  }
}

// ---------------- kernel 4: a[n], b[n] = relu(Z[n,:]) . w23 halves ------------
__global__ __launch_bounds__(256) void nodered_kernel(const float* __restrict__ part,
                                                      const float* __restrict__ w23,
                                                      float* __restrict__ aarr,
                                                      float* __restrict__ barr,
                                                      int ksplit){
  const int lane = threadIdx.x & 63;
  const int wv   = threadIdx.x >> 6;
  const int n    = blockIdx.x * 4 + wv;
  const float* p = part + (size_t)n * HID;
  float z1 = 0.f, z2 = 0.f;
  for (int s = 0; s < ksplit; ++s){
    const size_t o = (size_t)s * N_NODES * HID;
    z1 += p[o + lane];
    z2 += p[o + lane + 64];
  }
  z1 = fmaxf(z1, 0.f); z2 = fmaxf(z2, 0.f);
  float av = z1 * w23[lane]       + z2 * w23[lane + 64];
  float bv = z1 * w23[128 + lane] + z2 * w23[192 + lane];
#pragma unroll
  for (int o = 32; o > 0; o >>= 1){
    av += __shfl_down(av, o);
    bv += __shfl_down(bv, o);
  }
  if (lane == 0){ aarr[n] = av; barr[n] = bv; }
}

// ---------------- kernel 5: out[e] = sigmoid(a[i] + b[j]) ---------------------
__global__ __launch_bounds__(256) void edge_kernel(const int* __restrict__ e0,
                                                   const int* __restrict__ e1,
                                                   const float* __restrict__ aarr,
                                                   const float* __restrict__ barr,
                                                   float* __restrict__ out){
  const int e = blockIdx.x * 256 + threadIdx.x;
  int i, j;
  if (e < E_POS_N){ i = e0[2 * e];  j = e0[2 * e + 1]; }
  else { const int ee = e - E_POS_N; i = e1[2 * ee]; j = e1[2 * ee + 1]; }
  const float h = aarr[i] + barr[j];
  out[e] = 1.0f / (1.0f + __expf(-h));
}

extern "C" void kernel_launch(void* const* d_in, const int* in_sizes, int n_in,
                              void* d_out, int out_size, void* d_ws, size_t ws_size,
                              hipStream_t stream){
  const float* X   = (const float*)d_in[0];
  const float* adj = (const float*)d_in[1];
  const float* W   = (const float*)d_in[2];
  const float* W2  = (const float*)d_in[3];
  const float* W3  = (const float*)d_in[4];
  const int*   e0  = (const int*)d_in[5];
  const int*   e1  = (const int*)d_in[6];
  float* out = (float*)d_out;

  char* wsb = (char*)d_ws;
  unsigned short* bfB = (unsigned short*)(wsb);                            // 8 MB
  float* w23  = (float*)(wsb + (size_t)8 * 1024 * 1024);                   // 1 KB
  float* aarr = (float*)(wsb + (size_t)8 * 1024 * 1024 + 65536);           // 64 KB
  float* barr = (float*)(wsb + (size_t)8 * 1024 * 1024 + 2 * 65536);       // 64 KB
  float* part = (float*)(wsb + (size_t)16 * 1024 * 1024);                  // ksplit * 8 MB

  const size_t PART = (size_t)N_NODES * HID * 4;
  const size_t base = (size_t)16 * 1024 * 1024;
  int ksplit = 1;
  if (ws_size >= base + 4 * PART) ksplit = 4;
  else if (ws_size >= base + 2 * PART) ksplit = 2;

  hipLaunchKernelGGL(xw_kernel, dim3(N_NODES / 64), dim3(256), 0, stream, X, W, bfB);
  hipLaunchKernelGGL(w23_kernel, dim3(1), dim3(256), 0, stream, W2, W3, w23);
  hipLaunchKernelGGL(zgemm_kernel, dim3(64 * ksplit), dim3(512), 0, stream,
                     adj, bfB, part, ksplit);
  hipLaunchKernelGGL(nodered_kernel, dim3(N_NODES / 4), dim3(256), 0, stream,
                     part, w23, aarr, barr, ksplit);
  hipLaunchKernelGGL(edge_kernel, dim3(E_TOT / 256), dim3(256), 0, stream,
                     e0, e1, aarr, barr, out);
}